// Round 20
// baseline (276.765 us; speedup 1.0000x reference)
//
#include <hip/hip_runtime.h>

typedef _Float16 f16;
typedef f16 f16x4 __attribute__((ext_vector_type(4)));
typedef f16 f16x8 __attribute__((ext_vector_type(8)));
typedef float f32x4 __attribute__((ext_vector_type(4)));
typedef unsigned int u32;
typedef unsigned long long u64;

#define DEV static __device__ __forceinline__

// Problem constants: B=2, S=2048, D=1024, H=16, HD=64
#define S_ 2048
#define D_ 1024

// counted waitcnt: keep loads in flight across barriers (T4)
#define S_WAITV(n) asm volatile("s_waitcnt vmcnt(" #n ") lgkmcnt(0)" ::: "memory")
#define LGKM0_SB() do { asm volatile("s_waitcnt lgkmcnt(0)" ::: "memory"); \
                        __builtin_amdgcn_sched_barrier(0); } while (0)

// ---------------- helpers ----------------
// XOR swizzle for 64-elem (128B) f16 rows: 8 chunks of 8 f16 (16B)
DEV int swz64(int row, int chunk) { return row * 64 + (((chunk ^ row) & 7) << 3); }

// async global->LDS, 16B per lane. lds base must be wave-uniform; lane writes base+lane*16.
DEV void gload16(const void* g, void* l) {
    __builtin_amdgcn_global_load_lds((const __attribute__((address_space(1))) u32*)g,
                                     (__attribute__((address_space(3))) u32*)l, 16, 0, 0);
}
// v_exp_f32: 2^x
DEV float exp2_fast(float x) { float r; asm("v_exp_f32 %0, %1" : "=v"(r) : "v"(x)); return r; }

// ---------------- fp32 -> fp16 convert (x, W_attn, W_proj) ----------------
__global__ void convert_f16(const float* __restrict__ x, const float* __restrict__ wa,
                            const float* __restrict__ wp,
                            f16* __restrict__ xb, f16* __restrict__ wab, f16* __restrict__ wpb) {
    u32 t = blockIdx.x * blockDim.x + threadIdx.x;
    u32 base = t * 8u;                    // 8,388,608 total elems
    const float* src; f16* dst; u32 off;
    if (base < 4194304u)      { src = x;  dst = xb;  off = base; }
    else if (base < 7340032u) { src = wa; dst = wab; off = base - 4194304u; }
    else                      { src = wp; dst = wpb; off = base - 7340032u; }
    float4 a = *(const float4*)(src + off);
    float4 b = *(const float4*)(src + off + 4);
    f16x8 v;
    v[0] = (f16)a.x; v[1] = (f16)a.y; v[2] = (f16)a.z; v[3] = (f16)a.w;
    v[4] = (f16)b.x; v[5] = (f16)b.y; v[6] = (f16)b.z; v[7] = (f16)b.w;
    *(f16x8*)(dst + off) = v;
}

// ---------------- GEMM (A[M][K] * Bt[N][K]^T), 128x128 tile, BK=32 ----------------
// (unchanged — T4 pipelined, 3-slot ring)
template <int EPI>
__global__ __launch_bounds__(256) void gemm_bt(
    const f16* __restrict__ A, const f16* __restrict__ Bt, int K,
    f16* __restrict__ oQ, f16* __restrict__ oK, f16* __restrict__ oV,
    float* __restrict__ oY, const float* __restrict__ bias) {
    __shared__ f16 smem[3][8192];        // ring: [slot][As 4096 | Bs 4096] = 48 KB
    f16* sm = &smem[0][0];               // flat alias for V-epilogue scratch
    const int tid = threadIdx.x;
    const int lane = tid & 63;
    const int la = lane & 15, lg = lane >> 4;
    const int wv = tid >> 6;
    const int wr = (wv >> 1) << 6, wc = (wv & 1) << 6;
    const int r0 = blockIdx.x << 7, c0 = blockIdx.y << 7;

    const f32x4 VZ = {0.f, 0.f, 0.f, 0.f};
    f32x4 acc[4][4];
#pragma unroll
    for (int m = 0; m < 4; ++m)
#pragma unroll
        for (int n = 0; n < 4; ++n) acc[m][n] = VZ;

    const int srow = tid >> 2, scol = (tid & 3) << 3;
    const f16* Ag = A + (u64)(r0 + srow) * K + scol;
    const f16* Bg = Bt + (u64)(c0 + srow) * K + scol;
    const u64 K64 = (u64)K << 6;   // +64 rows

    const int NT = K >> 5;
#define STAGE(k0, slot)                                              \
    do {                                                             \
        f16* Al = smem[slot] + wv * 512;                             \
        f16* Bl = smem[slot] + 4096 + wv * 512;                      \
        gload16(Ag + (k0), Al);                                      \
        gload16(Ag + K64 + (k0), Al + 2048);                         \
        gload16(Bg + (k0), Bl);                                      \
        gload16(Bg + K64 + (k0), Bl + 2048);                         \
    } while (0)

    STAGE(0, 0);
    STAGE(32, 1);
    S_WAITV(4);                      // tile 0 resident; tile 1 stays in flight
    __builtin_amdgcn_s_barrier();

    for (int t = 0; t < NT; ++t) {
        if (t > 0) {
            if (t < NT - 1) { S_WAITV(4); } else { S_WAITV(0); }
            __builtin_amdgcn_s_barrier();
        }
        if (t + 2 < NT) STAGE((t + 2) << 5, (t + 2) % 3);
        const f16* As = smem[t % 3];
        const f16* Bs = smem[t % 3] + 4096;
        f16x8 af[4], bf[4];
#pragma unroll
        for (int m = 0; m < 4; ++m) af[m] = *(const f16x8*)(As + (wr + m * 16 + la) * 32 + lg * 8);
#pragma unroll
        for (int n = 0; n < 4; ++n) bf[n] = *(const f16x8*)(Bs + (wc + n * 16 + la) * 32 + lg * 8);
#pragma unroll
        for (int m = 0; m < 4; ++m)
#pragma unroll
            for (int n = 0; n < 4; ++n)
                acc[m][n] = __builtin_amdgcn_mfma_f32_16x16x32_f16(af[m], bf[n], acc[m][n], 0, 0, 0);
    }
#undef STAGE

    if (EPI == 0) {
        if (c0 < 2048) {
#pragma unroll
            for (int n = 0; n < 4; ++n) {
                int col = c0 + wc + n * 16 + la;   // 0..2047
#pragma unroll
                for (int m = 0; m < 4; ++m) {
#pragma unroll
                    for (int j = 0; j < 4; ++j) {
                        int row = r0 + wr + m * 16 + lg * 4 + j;  // 0..4095
                        int b = row >> 11, s = row & 2047;
                        float val = acc[m][n][j];
                        if (col < 1024) {
                            int h = col >> 6, hd = col & 63;
                            oQ[(((u64)(b * 16 + h)) * 2048 + s) * 64 + hd] = (f16)(val * 0.18033688f);
                        } else {
                            int d = col - 1024, h = d >> 6, hd = d & 63;
                            oK[(((u64)(b * 16 + h)) * 2048 + s) * 64 + hd] = (f16)val;
                        }
                    }
                }
            }
        } else {
            const int hbase = (c0 - 2048) >> 6;
            const int b = r0 >> 11, sb = r0 & 2047;
#pragma unroll
            for (int hh = 0; hh < 2; ++hh) {
                __syncthreads();
                if ((wv & 1) == hh) {
#pragma unroll
                    for (int n = 0; n < 4; ++n) {
                        int hd = n * 16 + la;
#pragma unroll
                        for (int m = 0; m < 4; ++m) {
                            int s = wr + m * 16 + lg * 4;
                            int pos = (s & ~31) | (lg << 3) | (((s >> 4) & 1) << 2);
                            f16x4 pk;
                            pk[0] = (f16)acc[m][n][0]; pk[1] = (f16)acc[m][n][1];
                            pk[2] = (f16)acc[m][n][2]; pk[3] = (f16)acc[m][n][3];
                            *(f16x4*)(sm + hd * 136 + pos) = pk;
                        }
                    }
                }
                __syncthreads();
                {
                    int hd = tid >> 2, qtr = tid & 3;
                    f16* dst = oV + (((u64)(b * 16 + hbase + hh)) * 64 + hd) * 2048 + sb + qtr * 32;
#pragma unroll
                    for (int i = 0; i < 4; ++i)
                        *(f16x8*)(dst + i * 8) = *(const f16x8*)(sm + hd * 136 + qtr * 32 + i * 8);
                }
            }
        }
    } else {
#pragma unroll
        for (int n = 0; n < 4; ++n) {
            int col = c0 + wc + n * 16 + la;
            float bv = bias[col];
#pragma unroll
            for (int m = 0; m < 4; ++m)
#pragma unroll
                for (int j = 0; j < 4; ++j) {
                    int row = r0 + wr + m * 16 + lg * 4 + j;
                    oY[(u64)row * 1024 + col] = acc[m][n][j] + bv;
                }
        }
    }
}

// ---------------- fused attention — BARRIER-FREE, 1 wave per block ----------------
// (R19 design; compile fix only: no const arrays of LDS pointers — inline
// arithmetic instead, which hipcc accepts.)
// Rationale: R17 probe showed attn's store pattern alone = 6.1 TB/s; read BW,
// load latency, nt, store runway all tested null -> residual is the barrier
// lock-step. Each block = ONE wave owning 16 q-rows with private K/V dbufs
// (16KB/block -> 10 independent blocks/CU, free-running like the probe).
// Per-wave FIFO audits (no cross-wave hazards):
//  pass1 (4 loads/iter): steady queue [L(kt)4, L(kt+1)4] -> wait(4); kt=63 wait(0).
//  pass2 (8 loads + 2 stores/iter, order: compute,stores,prefetch):
//    queue [L(kt)8, S(kt-1)2, L(kt+1)8]=18 -> wait(10); kt=63: [L63,S62]=10 -> wait(2).
//  Slot WAR (prefetch overwrites slot just read): lgkmcnt(0)+sched_barrier(0).
__global__ __launch_bounds__(64) void attn_fused(
    const f16* __restrict__ q, const f16* __restrict__ k, const f16* __restrict__ vt,
    float* __restrict__ att, f16* __restrict__ ya) {
    __shared__ f16 smem[8192];   // 16KB: K0 | K1 | V0 | V1 (2048 f16 each)

    const int lane = threadIdx.x & 63;
    const int la = lane & 15, lg = lane >> 4;
    const int bh = blockIdx.x, qw = blockIdx.y;   // bh on x => head-per-XCD grouping
    const f16* qh = q + (u64)bh * (S_ * 64) + qw * (16 * 64);
    const f16* kh = k + (u64)bh * (S_ * 64);
    const f16* vh = vt + (u64)bh * (S_ * 64);   // [64 hd][2048 permuted keys]

    // K/Q staging (128B rows): issue i covers rows i*8 + (lane>>3); row&7 == kr
    const int kr = lane >> 3;
    const int kc = ((lane & 7) ^ kr) << 3;
    // V staging (64B rows): issue i covers rows i*16 + (lane>>2); row&3 == vr&3
    const int vr = lane >> 2;
    const int vc = ((lane & 3) ^ (vr & 3)) << 3;

#define STK(kt, sl) do { const f16* kb_ = kh + (u64)(kt) * 2048;              \
        f16* d_ = smem + (sl) * 2048;                                         \
        gload16(kb_ + (u64)(0 * 8 + kr) * 64 + kc, d_);                       \
        gload16(kb_ + (u64)(1 * 8 + kr) * 64 + kc, d_ + 512);                 \
        gload16(kb_ + (u64)(2 * 8 + kr) * 64 + kc, d_ + 1024);                \
        gload16(kb_ + (u64)(3 * 8 + kr) * 64 + kc, d_ + 1536); } while (0)
#define STV(kt, sl) do { const f16* vb_ = vh + (u64)(kt) * 32 + vc;           \
        f16* d_ = smem + 4096 + (sl) * 2048;                                  \
        gload16(vb_ + (u64)(0 * 16 + vr) * 2048, d_);                         \
        gload16(vb_ + (u64)(1 * 16 + vr) * 2048, d_ + 512);                   \
        gload16(vb_ + (u64)(2 * 16 + vr) * 2048, d_ + 1024);                  \
        gload16(vb_ + (u64)(3 * 16 + vr) * 2048, d_ + 1536); } while (0)

    // ---- stage Q (16x64, 2KB) through V0 slot; hoist to regs
    {
        f16* qstage = smem + 4096;
        gload16(qh + (u64)kr * 64 + kc, qstage);
        gload16(qh + (u64)(8 + kr) * 64 + kc, qstage + 512);
        S_WAITV(0);
    }
    f16x8 qf[2];
    qf[0] = *(const f16x8*)(smem + 4096 + swz64(la, lg));
    qf[1] = *(const f16x8*)(smem + 4096 + swz64(la, 4 + lg));
    LGKM0_SB();

    const f32x4 VZ = {0.f, 0.f, 0.f, 0.f};
    float psum = 0.f;

    // ---- pass 1: row sums of 2^scores (lane-local: q=la); private K dbuf
    STK(0, 0);
    STK(1, 1);
    S_WAITV(4);                        // K0 resident; K1 flying
    for (int kt = 0; kt < 64; ++kt) {
        if (kt > 0) { if (kt < 63) { S_WAITV(4); } else { S_WAITV(0); } }
        const f16* kcur = smem + (kt & 1) * 2048;
        f32x4 sc[2] = {VZ, VZ};
#pragma unroll
        for (int ch = 0; ch < 2; ++ch)
#pragma unroll
            for (int n = 0; n < 2; ++n) {
                f16x8 kf = *(const f16x8*)(kcur + swz64(n * 16 + la, ch * 4 + lg));
                sc[n] = __builtin_amdgcn_mfma_f32_16x16x32_f16(kf, qf[ch], sc[n], 0, 0, 0);
            }
#pragma unroll
        for (int n = 0; n < 2; ++n)
#pragma unroll
            for (int j = 0; j < 4; ++j) psum += exp2_fast(sc[n][j]);
        if (kt < 62) {                 // prefetch K(kt+2) into the slot just read
            LGKM0_SB();
            STK(kt + 2, (kt & 1));
        }
    }
    // reduce across the 4 lg-groups (lanes la, la+16, la+32, la+48 share q=la)
    psum += __shfl_xor(psum, 16);
    psum += __shfl_xor(psum, 32);
    const float invl = 1.0f / psum;
    LGKM0_SB();                        // pass-1 ds_reads done before restaging

    // ---- pass 2: private K/V dbufs; scores -> att (plain f32x4) -> PV
    STK(0, 0); STV(0, 0);
    STK(1, 1); STV(1, 1);
    S_WAITV(8);                        // K0,V0 resident; K1,V1 flying
    f32x4 accy[4] = {VZ, VZ, VZ, VZ};
    float* ab = att + ((u64)bh * S_ + (u64)qw * 16 + la) * S_ + (lg << 2);
    for (int kt = 0; kt < 64; ++kt) {
        if (kt > 0) { if (kt < 63) { S_WAITV(10); } else { S_WAITV(2); } }
        const f16* kcur = smem + (kt & 1) * 2048;
        const f16* vcur = smem + 4096 + (kt & 1) * 2048;

        f32x4 sc[2] = {VZ, VZ};
#pragma unroll
        for (int ch = 0; ch < 2; ++ch)
#pragma unroll
            for (int n = 0; n < 2; ++n) {
                f16x8 kf = *(const f16x8*)(kcur + swz64(n * 16 + la, ch * 4 + lg));
                sc[n] = __builtin_amdgcn_mfma_f32_16x16x32_f16(kf, qf[ch], sc[n], 0, 0, 0);
            }
        // p = 2^s * invl; lane holds q=la, keys kt*32 + n*16 + lg*4 + j
        f32x4 pp[2];
#pragma unroll
        for (int n = 0; n < 2; ++n) {
#pragma unroll
            for (int j = 0; j < 4; ++j) pp[n][j] = exp2_fast(sc[n][j]) * invl;
            *(f32x4*)(ab + kt * 32 + n * 16) = pp[n];
        }
        // pack A-fragment (permuted V^T slot order: slot = lg*8 + n*4 + j)
        f16x8 pa;
#pragma unroll
        for (int j = 0; j < 4; ++j) { pa[j] = (f16)pp[0][j]; pa[j + 4] = (f16)pp[1][j]; }
#pragma unroll
        for (int n = 0; n < 4; ++n) {
            f16x8 vf = *(const f16x8*)(vcur + (n * 16 + la) * 32 + ((lg ^ (la & 3)) << 3));
            accy[n] = __builtin_amdgcn_mfma_f32_16x16x32_f16(pa, vf, accy[n], 0, 0, 0);
        }
        if (kt < 62) {                 // prefetch K/V(kt+2) into the slots just read
            LGKM0_SB();
            STK(kt + 2, (kt & 1));
            STV(kt + 2, (kt & 1));
        }
    }
#undef STK
#undef STV

    const int b = bh >> 4, h = bh & 15;
    f16* yb = ya + ((u64)b * S_ + qw * 16) * D_ + h * 64;
#pragma unroll
    for (int n = 0; n < 4; ++n)
#pragma unroll
        for (int j = 0; j < 4; ++j)
            yb[(u64)(lg * 4 + j) * D_ + n * 16 + la] = (f16)accy[n][j];
}

// ---------------- launcher ----------------
extern "C" void kernel_launch(void* const* d_in, const int* in_sizes, int n_in,
                              void* d_out, int out_size, void* d_ws, size_t ws_size,
                              hipStream_t stream) {
    const float* x  = (const float*)d_in[0];
    const float* wa = (const float*)d_in[1];
    const float* wp = (const float*)d_in[2];
    const float* bp = (const float*)d_in[3];
    float* outY   = (float*)d_out;            // [2,2048,1024]
    float* outAtt = outY + 4194304ull;        // [2,16,2048,2048]

    char* ws = (char*)d_ws;                   // ~48 MB used
    f16* xb  = (f16*)(ws + 0);                // [4096][1024]
    f16* wab = (f16*)(ws + 8388608);          // [3072][1024]
    f16* wpb = (f16*)(ws + 14680064);         // [1024][1024]
    f16* qb  = (f16*)(ws + 16777216);         // [bh][s][64] (pre-scaled log2e/8)
    f16* kb  = (f16*)(ws + 25165824);         // [bh][s][64]
    f16* vtb = (f16*)(ws + 33554432);         // [bh][64 hd][2048 s'] (V^T, key-permuted)
    f16* yab = (f16*)(ws + 41943040);         // [4096][1024]

    convert_f16<<<4096, 256, 0, stream>>>(x, wa, wp, xb, wab, wpb);
    gemm_bt<0><<<dim3(32, 24), 256, 0, stream>>>(xb, wab, 1024, qb, kb, vtb, nullptr, nullptr);
    attn_fused<<<dim3(32, 128), 64, 0, stream>>>(qb, kb, vtb, outAtt, yab);  // 1-wave blocks
    gemm_bt<1><<<dim3(32, 8), 256, 0, stream>>>(yab, wpb, 1024, nullptr, nullptr, nullptr, outY, bp);
}

// Round 21
// 226.487 us; speedup vs baseline: 1.2220x; 1.2220x over previous
//
#include <hip/hip_runtime.h>

typedef _Float16 f16;
typedef f16 f16x4 __attribute__((ext_vector_type(4)));
typedef f16 f16x8 __attribute__((ext_vector_type(8)));
typedef float f32x4 __attribute__((ext_vector_type(4)));
typedef unsigned int u32;
typedef unsigned long long u64;

#define DEV static __device__ __forceinline__

// Problem constants: B=2, S=2048, D=1024, H=16, HD=64
#define S_ 2048
#define D_ 1024

// counted waitcnt: keep loads in flight across barriers (T4)
#define S_WAITV(n) asm volatile("s_waitcnt vmcnt(" #n ") lgkmcnt(0)" ::: "memory")

// ---------------- helpers ----------------
// XOR swizzle for 64-elem (128B) f16 rows: 8 chunks of 8 f16 (16B)
DEV int swz64(int row, int chunk) { return row * 64 + (((chunk ^ row) & 7) << 3); }

// async global->LDS, 16B per lane. lds base must be wave-uniform; lane writes base+lane*16.
DEV void gload16(const void* g, void* l) {
    __builtin_amdgcn_global_load_lds((const __attribute__((address_space(1))) u32*)g,
                                     (__attribute__((address_space(3))) u32*)l, 16, 0, 0);
}
// v_exp_f32: 2^x
DEV float exp2_fast(float x) { float r; asm("v_exp_f32 %0, %1" : "=v"(r) : "v"(x)); return r; }
// streaming store: bypasses L2/L3
DEV void nt_store4(float* p, f32x4 v) { __builtin_nontemporal_store(v, (f32x4*)p); }

// ---------------- fp32 -> fp16 convert (x, W_attn, W_proj) ----------------
__global__ void convert_f16(const float* __restrict__ x, const float* __restrict__ wa,
                            const float* __restrict__ wp,
                            f16* __restrict__ xb, f16* __restrict__ wab, f16* __restrict__ wpb) {
    u32 t = blockIdx.x * blockDim.x + threadIdx.x;
    u32 base = t * 8u;                    // 8,388,608 total elems
    const float* src; f16* dst; u32 off;
    if (base < 4194304u)      { src = x;  dst = xb;  off = base; }
    else if (base < 7340032u) { src = wa; dst = wab; off = base - 4194304u; }
    else                      { src = wp; dst = wpb; off = base - 7340032u; }
    float4 a = *(const float4*)(src + off);
    float4 b = *(const float4*)(src + off + 4);
    f16x8 v;
    v[0] = (f16)a.x; v[1] = (f16)a.y; v[2] = (f16)a.z; v[3] = (f16)a.w;
    v[4] = (f16)b.x; v[5] = (f16)b.y; v[6] = (f16)b.z; v[7] = (f16)b.w;
    *(f16x8*)(dst + off) = v;
}

// ---------------- GEMM (A[M][K] * Bt[N][K]^T), 128x128 tile, BK=32 ----------------
// T4 pipelined: 3-slot LDS ring, 2-tiles-ahead global_load_lds prefetch,
// per-iter [vmcnt(4) lgkmcnt(0)] -> s_barrier -> STAGE(t+2) -> ds_read+MFMA.
// EPI==0: QKV epilogue -> q*(0.125*log2e) / k into [bh][s][64];
//         V TRANSPOSED+KEY-PERMUTED [bh][hd][S'] via LDS transpose (aliases ring)
// EPI==1: proj epilogue -> fp32 out + bias
template <int EPI>
__global__ __launch_bounds__(256) void gemm_bt(
    const f16* __restrict__ A, const f16* __restrict__ Bt, int K,
    f16* __restrict__ oQ, f16* __restrict__ oK, f16* __restrict__ oV,
    float* __restrict__ oY, const float* __restrict__ bias) {
    __shared__ f16 smem[3][8192];        // ring: [slot][As 4096 | Bs 4096] = 48 KB
    f16* sm = &smem[0][0];               // flat alias for V-epilogue scratch
    const int tid = threadIdx.x;
    const int lane = tid & 63;
    const int la = lane & 15, lg = lane >> 4;
    const int wv = tid >> 6;
    const int wr = (wv >> 1) << 6, wc = (wv & 1) << 6;
    const int r0 = blockIdx.x << 7, c0 = blockIdx.y << 7;

    const f32x4 VZ = {0.f, 0.f, 0.f, 0.f};
    f32x4 acc[4][4];
#pragma unroll
    for (int m = 0; m < 4; ++m)
#pragma unroll
        for (int n = 0; n < 4; ++n) acc[m][n] = VZ;

    const int srow = tid >> 2, scol = (tid & 3) << 3;
    const f16* Ag = A + (u64)(r0 + srow) * K + scol;
    const f16* Bg = Bt + (u64)(c0 + srow) * K + scol;
    const u64 K64 = (u64)K << 6;   // +64 rows

    const int NT = K >> 5;
#define STAGE(k0, slot)                                              \
    do {                                                             \
        f16* Al = smem[slot] + wv * 512;                             \
        f16* Bl = smem[slot] + 4096 + wv * 512;                      \
        gload16(Ag + (k0), Al);                                      \
        gload16(Ag + K64 + (k0), Al + 2048);                         \
        gload16(Bg + (k0), Bl);                                      \
        gload16(Bg + K64 + (k0), Bl + 2048);                         \
    } while (0)

    STAGE(0, 0);
    STAGE(32, 1);
    S_WAITV(4);                      // tile 0 resident; tile 1 stays in flight
    __builtin_amdgcn_s_barrier();

    for (int t = 0; t < NT; ++t) {
        if (t > 0) {
            if (t < NT - 1) { S_WAITV(4); } else { S_WAITV(0); }
            __builtin_amdgcn_s_barrier();
        }
        if (t + 2 < NT) STAGE((t + 2) << 5, (t + 2) % 3);
        const f16* As = smem[t % 3];
        const f16* Bs = smem[t % 3] + 4096;
        f16x8 af[4], bf[4];
#pragma unroll
        for (int m = 0; m < 4; ++m) af[m] = *(const f16x8*)(As + (wr + m * 16 + la) * 32 + lg * 8);
#pragma unroll
        for (int n = 0; n < 4; ++n) bf[n] = *(const f16x8*)(Bs + (wc + n * 16 + la) * 32 + lg * 8);
#pragma unroll
        for (int m = 0; m < 4; ++m)
#pragma unroll
            for (int n = 0; n < 4; ++n)
                acc[m][n] = __builtin_amdgcn_mfma_f32_16x16x32_f16(af[m], bf[n], acc[m][n], 0, 0, 0);
    }
#undef STAGE

    if (EPI == 0) {
        if (c0 < 2048) {
            // Q / K epilogue: [bh][s][hd] scatter (16-lane groups hit 32B contiguous)
#pragma unroll
            for (int n = 0; n < 4; ++n) {
                int col = c0 + wc + n * 16 + la;   // 0..2047
#pragma unroll
                for (int m = 0; m < 4; ++m) {
#pragma unroll
                    for (int j = 0; j < 4; ++j) {
                        int row = r0 + wr + m * 16 + lg * 4 + j;  // 0..4095
                        int b = row >> 11, s = row & 2047;
                        float val = acc[m][n][j];
                        if (col < 1024) {
                            int h = col >> 6, hd = col & 63;
                            // q pre-scaled by (1/8)*log2(e) so scores feed v_exp_f32 directly
                            oQ[(((u64)(b * 16 + h)) * 2048 + s) * 64 + hd] = (f16)(val * 0.18033688f);
                        } else {
                            int d = col - 1024, h = d >> 6, hd = d & 63;
                            oK[(((u64)(b * 16 + h)) * 2048 + s) * 64 + hd] = (f16)val;
                        }
                    }
                }
            }
        } else {
            // V epilogue: transpose + key-permute through LDS, coalesced [bh][hd][S'] stores.
            const int hbase = (c0 - 2048) >> 6;
            const int b = r0 >> 11, sb = r0 & 2047;
#pragma unroll
            for (int hh = 0; hh < 2; ++hh) {
                __syncthreads();
                if ((wv & 1) == hh) {   // waves holding these 64 cols
#pragma unroll
                    for (int n = 0; n < 4; ++n) {
                        int hd = n * 16 + la;
#pragma unroll
                        for (int m = 0; m < 4; ++m) {
                            int s = wr + m * 16 + lg * 4;   // base key, j=0..3 consecutive
                            int pos = (s & ~31) | (lg << 3) | (((s >> 4) & 1) << 2);
                            f16x4 pk;
                            pk[0] = (f16)acc[m][n][0]; pk[1] = (f16)acc[m][n][1];
                            pk[2] = (f16)acc[m][n][2]; pk[3] = (f16)acc[m][n][3];
                            *(f16x4*)(sm + hd * 136 + pos) = pk;
                        }
                    }
                }
                __syncthreads();
                {   // all 256 threads store out: thread -> (hd, 32-key group)
                    int hd = tid >> 2, qtr = tid & 3;
                    f16* dst = oV + (((u64)(b * 16 + hbase + hh)) * 64 + hd) * 2048 + sb + qtr * 32;
#pragma unroll
                    for (int i = 0; i < 4; ++i)
                        *(f16x8*)(dst + i * 8) = *(const f16x8*)(sm + hd * 136 + qtr * 32 + i * 8);
                }
            }
        }
    } else {
#pragma unroll
        for (int n = 0; n < 4; ++n) {
            int col = c0 + wc + n * 16 + la;
            float bv = bias[col];
#pragma unroll
            for (int m = 0; m < 4; ++m)
#pragma unroll
                for (int j = 0; j < 4; ++j) {
                    int row = r0 + wr + m * 16 + lg * 4 + j;
                    oY[(u64)row * 1024 + col] = acc[m][n][j] + bv;
                }
        }
    }
}

// ---------------- fused attention (R13 final — best measured: 229.4us) ----------------
// grid (32 bh, 32 qt), 4 waves; swapped QK^T (lane-local P); T4 counted-vmcnt
// double-buffered staging; att written via per-wave LDS transpose + full-line
// nt stores; PV contracted against key-permuted V^T directly from registers.
__global__ __launch_bounds__(256) void attn_fused(
    const f16* __restrict__ q, const f16* __restrict__ k, const f16* __restrict__ vt,
    float* __restrict__ att, f16* __restrict__ ya) {
    __shared__ f16 smem[25088];   // 50176B: slots 0-3 K/V dbuf, slot4 Q (dead->P), +extra
    f16* qs = smem + 4 * 4096;

    const int tid = threadIdx.x, lane = tid & 63, wv = tid >> 6;
    const int la = lane & 15, lg = lane >> 4;
    const int bh = blockIdx.x, qt = blockIdx.y;   // bh on x => one head per XCD
    const f16* qh = q + (u64)bh * (S_ * 64) + qt * (64 * 64);
    const f16* kh = k + (u64)bh * (S_ * 64);
    const f16* vh = vt + (u64)bh * (S_ * 64);   // [64 hd][2048 s']

    // per-wave P staging tile: 16 rows x 272B, starting at byte 32768 (Q slot)
    char* const Pw = (char*)smem + 32768 + wv * 4352;

    const int sr0 = wv * 8 + (lane >> 3);
    const int sr1 = sr0 + 32;
    const int sc0 = (((lane & 7) ^ (sr0 & 7)) << 3);
    const int sc1 = (((lane & 7) ^ (sr1 & 7)) << 3);
    const u64 go0 = (u64)sr0 * 64 + sc0, go1 = (u64)sr1 * 64 + sc1;       // K/Q offsets
    const u64 gv0 = (u64)sr0 * 2048 + sc0, gv1 = (u64)sr1 * 2048 + sc1;   // V^T offsets

    // ---- pass-1 prologue: stage Q, K0->slot0, K1->slot1
    gload16(qh + go0, qs + wv * 512);
    gload16(qh + go1, qs + 2048 + wv * 512);
    gload16(kh + go0, smem + wv * 512);
    gload16(kh + go1, smem + 2048 + wv * 512);
    gload16(kh + 4096 + go0, smem + 4096 + wv * 512);
    gload16(kh + 4096 + go1, smem + 4096 + 2048 + wv * 512);
    S_WAITV(2);                       // Q, K0 landed; K1 stays in flight
    __builtin_amdgcn_s_barrier();

    // hoist this wave's Q fragments to regs (q = wv*16 + la, hd chunk lg)
    f16x8 qf[2];
    qf[0] = *(const f16x8*)(qs + swz64(wv * 16 + la, lg));
    qf[1] = *(const f16x8*)(qs + swz64(wv * 16 + la, 4 + lg));

    const f32x4 VZ = {0.f, 0.f, 0.f, 0.f};
    float psum = 0.f;

    // ---- pass 1: row sums of 2^scores (lane-local: q=la)
    for (int kt = 0; kt < 32; ++kt) {
        if (kt > 0) {                 // iter0's tile already drained in prologue
            if (kt < 31) { S_WAITV(2); } else { S_WAITV(0); }
            __builtin_amdgcn_s_barrier();
        }
        if (kt < 30) {                // prefetch K(kt+2) into ring slot
            const f16* kb = kh + (kt + 2) * 4096;
            f16* dst = smem + ((kt + 2) % 3) * 4096;
            gload16(kb + go0, dst + wv * 512);
            gload16(kb + go1, dst + 2048 + wv * 512);
        }
        const f16* kcur = smem + (kt % 3) * 4096;
        f32x4 sc[4] = {VZ, VZ, VZ, VZ};
#pragma unroll
        for (int ch = 0; ch < 2; ++ch)
#pragma unroll
            for (int n = 0; n < 4; ++n) {
                f16x8 kf = *(const f16x8*)(kcur + swz64(n * 16 + la, ch * 4 + lg));
                sc[n] = __builtin_amdgcn_mfma_f32_16x16x32_f16(kf, qf[ch], sc[n], 0, 0, 0);
            }
#pragma unroll
        for (int n = 0; n < 4; ++n)
#pragma unroll
            for (int j = 0; j < 4; ++j) psum += exp2_fast(sc[n][j]);
    }
    S_WAITV(0);
    __builtin_amdgcn_s_barrier();

    // reduce across the 4 lg-groups (lanes la, la+16, la+32, la+48 share q=la)
    psum += __shfl_xor(psum, 16);
    psum += __shfl_xor(psum, 32);
    const float invl = 1.0f / psum;

    // ---- pass-2 prologue: stage K0->slot0, V0->slot2
    gload16(kh + go0, smem + wv * 512);
    gload16(kh + go1, smem + 2048 + wv * 512);
    gload16(vh + gv0, smem + 2 * 4096 + wv * 512);
    gload16(vh + gv1, smem + 2 * 4096 + 2048 + wv * 512);
    S_WAITV(0);
    __builtin_amdgcn_s_barrier();

    // ---- pass 2: recompute scores, PV from registers, att via LDS-transposed nt stores
    f32x4 accy[4] = {VZ, VZ, VZ, VZ};
    float* abw = att + ((u64)bh * S_ + (u64)qt * 64 + wv * 16) * S_;
    for (int kt = 0; kt < 32; ++kt) {
        if (kt > 0) {
            S_WAITV(4);               // drains K(kt),V(kt); last iter's 4 att stores fly
            __builtin_amdgcn_s_barrier();
        }
        if (kt < 31) {                // prefetch K(kt+1),V(kt+1) into the other slots
            const f16* kb = kh + (kt + 1) * 4096;
            const f16* vb = vh + (kt + 1) * 64;
            f16* kd = smem + ((kt + 1) & 1) * 4096;
            f16* vd = smem + (2 + ((kt + 1) & 1)) * 4096;
            gload16(kb + go0, kd + wv * 512);
            gload16(kb + go1, kd + 2048 + wv * 512);
            gload16(vb + gv0, vd + wv * 512);
            gload16(vb + gv1, vd + 2048 + wv * 512);
        }
        const f16* kcur = smem + (kt & 1) * 4096;
        const f16* vcur = smem + (2 + (kt & 1)) * 4096;

        f32x4 sc[4] = {VZ, VZ, VZ, VZ};
#pragma unroll
        for (int ch = 0; ch < 2; ++ch)
#pragma unroll
            for (int n = 0; n < 4; ++n) {
                f16x8 kf = *(const f16x8*)(kcur + swz64(n * 16 + la, ch * 4 + lg));
                sc[n] = __builtin_amdgcn_mfma_f32_16x16x32_f16(kf, qf[ch], sc[n], 0, 0, 0);
            }
        // p = 2^s * invl; lane holds q=la, k = kt*64 + n*16 + lg*4 + j (j contiguous)
        f32x4 pp[4];
#pragma unroll
        for (int n = 0; n < 4; ++n) {
#pragma unroll
            for (int j = 0; j < 4; ++j) pp[n][j] = exp2_fast(sc[n][j]) * invl;
            // stage into P-LDS (row la, bytes n*64 + lg*16; 272B stride -> 2-way-free)
            *(f32x4*)(Pw + la * 272 + n * 64 + lg * 16) = pp[n];
        }
        // pack A-fragments for PV (slot order matches permuted V^T layout)
        f16x8 pa0, pa1;
#pragma unroll
        for (int j = 0; j < 4; ++j) {
            pa0[j] = (f16)pp[0][j]; pa0[j + 4] = (f16)pp[1][j];
            pa1[j] = (f16)pp[2][j]; pa1[j + 4] = (f16)pp[3][j];
        }
#pragma unroll
        for (int n = 0; n < 4; ++n) {
            f16x8 vf0 = *(const f16x8*)(vcur + swz64(n * 16 + la, lg));
            accy[n] = __builtin_amdgcn_mfma_f32_16x16x32_f16(pa0, vf0, accy[n], 0, 0, 0);
            f16x8 vf1 = *(const f16x8*)(vcur + swz64(n * 16 + la, 4 + lg));
            accy[n] = __builtin_amdgcn_mfma_f32_16x16x32_f16(pa1, vf1, accy[n], 0, 0, 0);
        }
        // coalesced readback + full-line nt store (hidden under the PV MFMAs above)
#pragma unroll
        for (int r = 0; r < 4; ++r) {
            int row = r * 4 + (lane >> 4);
            f32x4 v = *(const f32x4*)(Pw + row * 272 + (lane & 15) * 16);
            nt_store4(abw + (u64)row * S_ + kt * 64 + (lane & 15) * 4, v);
        }
    }

    const int b = bh >> 4, h = bh & 15;
    f16* yb = ya + ((u64)b * S_ + qt * 64 + wv * 16) * D_ + h * 64;
#pragma unroll
    for (int n = 0; n < 4; ++n)
#pragma unroll
        for (int j = 0; j < 4; ++j)
            yb[(u64)(lg * 4 + j) * D_ + n * 16 + la] = (f16)accy[n][j];
}

// ---------------- launcher ----------------
extern "C" void kernel_launch(void* const* d_in, const int* in_sizes, int n_in,
                              void* d_out, int out_size, void* d_ws, size_t ws_size,
                              hipStream_t stream) {
    const float* x  = (const float*)d_in[0];
    const float* wa = (const float*)d_in[1];
    const float* wp = (const float*)d_in[2];
    const float* bp = (const float*)d_in[3];
    float* outY   = (float*)d_out;            // [2,2048,1024]
    float* outAtt = outY + 4194304ull;        // [2,16,2048,2048]

    char* ws = (char*)d_ws;                   // ~48 MB used
    f16* xb  = (f16*)(ws + 0);                // [4096][1024]
    f16* wab = (f16*)(ws + 8388608);          // [3072][1024]
    f16* wpb = (f16*)(ws + 14680064);         // [1024][1024]
    f16* qb  = (f16*)(ws + 16777216);         // [bh][s][64] (pre-scaled log2e/8)
    f16* kb  = (f16*)(ws + 25165824);         // [bh][s][64]
    f16* vtb = (f16*)(ws + 33554432);         // [bh][64 hd][2048 s'] (V^T, key-permuted)
    f16* yab = (f16*)(ws + 41943040);         // [4096][1024]

    convert_f16<<<4096, 256, 0, stream>>>(x, wa, wp, xb, wab, wpb);
    gemm_bt<0><<<dim3(32, 24), 256, 0, stream>>>(xb, wab, 1024, qb, kb, vtb, nullptr, nullptr);
    attn_fused<<<dim3(32, 32), 256, 0, stream>>>(qb, kb, vtb, outAtt, yab);  // grid=(bh,qt)
    gemm_bt<1><<<dim3(32, 8), 256, 0, stream>>>(yab, wpb, 1024, nullptr, nullptr, nullptr, outY, bp);
}